// Round 1
// baseline (334.742 us; speedup 1.0000x reference)
//
#include <hip/hip_runtime.h>

typedef short bf16x8 __attribute__((ext_vector_type(8)));
typedef float f32x4 __attribute__((ext_vector_type(4)));

#define NG   9
#define CIN  1152
#define IG1  128
#define OG1  512
#define IG2  512
#define OG2  128
#define KP   576      // padded K per g2 (9 runs * 64)
#define HROW 5184     // NG * KP
#define MTOT 16384

__device__ __forceinline__ short f2bf(float f) {
    unsigned u = __float_as_uint(f);
    u += 0x7fff + ((u >> 16) & 1);   // RNE
    return (short)(u >> 16);
}

// ---- prep: W1 fp32 -> bf16 (layout kept: [9][512][128], k contiguous)
__global__ __launch_bounds__(256) void prep_w1(const float* __restrict__ w1, short* __restrict__ w1b) {
    int i = blockIdx.x * 256 + threadIdx.x;
    if (i < NG * OG1 * IG1) w1b[i] = f2bf(w1[i]);
}

// ---- prep: W2p[g2][o2][kp] permuted + zero-padded bf16
// kp = g1*64 + r  ->  o = olo(g1,g2)+r, j = 9*o + g1 - 512*g2 ; valid iff j < 512
__global__ __launch_bounds__(256) void prep_w2(const float* __restrict__ w2, short* __restrict__ w2p) {
    int i = blockIdx.x * 256 + threadIdx.x;
    if (i >= NG * OG2 * KP) return;
    int g2  = i / (OG2 * KP);
    int rem = i - g2 * (OG2 * KP);
    int o2  = rem / KP;
    int kp  = rem - o2 * KP;
    int g1 = kp >> 6, r = kp & 63;
    int olo = (512 * g2 - g1 + 8) / 9;           // ceil((512g2-g1)/9), numerator >= 0
    int j = 9 * (olo + r) + g1 - 512 * g2;       // >= 0 by construction
    float v = (j < 512) ? w2[(g2 * OG2 + o2) * IG2 + j] : 0.0f;
    w2p[i] = f2bf(v);
}

// ---- layer 1: per (m-tile 128, g1): X[128x128] @ W1[g1]^T -> hardswish -> hbuf
__global__ __launch_bounds__(256) void k1(const float* __restrict__ x, const short* __restrict__ w1b,
                                          const float* __restrict__ b1, short* __restrict__ hbuf) {
    __shared__ short As[128 * 16 * 8];   // [row][granule16][8] XOR-swizzled, 32 KB
    __shared__ short Bs[64 * 16 * 8];    // 16 KB
    const int t = threadIdx.x;
    const int mt = blockIdx.x, g1 = blockIdx.y;
    const int m0 = mt * 128;

    // stage A: x tile 128x128 fp32 -> bf16, swizzled
    for (int i = 0; i < 8; ++i) {
        int flat = (i * 256 + t) * 8;
        int row = flat >> 7, col = flat & 127;
        const float* gp = x + (size_t)(m0 + row) * CIN + g1 * IG1 + col;
        float4 v0 = *(const float4*)gp;
        float4 v1 = *(const float4*)(gp + 4);
        bf16x8 s;
        s[0]=f2bf(v0.x); s[1]=f2bf(v0.y); s[2]=f2bf(v0.z); s[3]=f2bf(v0.w);
        s[4]=f2bf(v1.x); s[5]=f2bf(v1.y); s[6]=f2bf(v1.z); s[7]=f2bf(v1.w);
        int g = col >> 3;
        *(bf16x8*)&As[(row * 16 + (g ^ (row & 7))) * 8] = s;
    }

    const int lane = t & 63, w = t >> 6;
    const int wr = w >> 1, wc = w & 1;       // 2x2 waves; wave tile 64 rows x 32 cols
    const int lr = lane & 15, lg = lane >> 4;

    for (int nt = 0; nt < 8; ++nt) {         // o-tiles of 64 (512 total)
        __syncthreads();
        // stage B: w1b[g1][nt*64+row][col], 64x128
        for (int i = 0; i < 4; ++i) {
            int flat = (i * 256 + t) * 8;
            int row = flat >> 7, col = flat & 127;
            bf16x8 s = *(const bf16x8*)(w1b + ((g1 * OG1 + nt * 64 + row) * IG1 + col));
            int g = col >> 3;
            *(bf16x8*)&Bs[(row * 16 + (g ^ (row & 7))) * 8] = s;
        }
        __syncthreads();

        f32x4 acc[4][2];
        for (int mi = 0; mi < 4; ++mi) for (int ni = 0; ni < 2; ++ni) acc[mi][ni] = (f32x4){0.f,0.f,0.f,0.f};
        for (int kk = 0; kk < 4; ++kk) {
            int gk = kk * 4 + lg;
            bf16x8 af[4], bfr[2];
            for (int mi = 0; mi < 4; ++mi) {
                int row = wr * 64 + mi * 16 + lr;
                af[mi] = *(const bf16x8*)&As[(row * 16 + (gk ^ (row & 7))) * 8];
            }
            for (int ni = 0; ni < 2; ++ni) {
                int rb = wc * 32 + ni * 16 + lr;
                bfr[ni] = *(const bf16x8*)&Bs[(rb * 16 + (gk ^ (rb & 7))) * 8];
            }
            for (int mi = 0; mi < 4; ++mi)
                for (int ni = 0; ni < 2; ++ni)
                    acc[mi][ni] = __builtin_amdgcn_mfma_f32_16x16x32_bf16(af[mi], bfr[ni], acc[mi][ni], 0, 0, 0);
        }

        // epilogue: bias + hardswish -> bf16 -> hbuf (padded-run layout)
        for (int ni = 0; ni < 2; ++ni) {
            int o = nt * 64 + wc * 32 + ni * 16 + lr;
            float bias = b1[g1 * OG1 + o];
            int c  = 9 * o + g1;
            int g2 = c >> 9;
            int olo = (512 * g2 - g1 + 8) / 9;
            int hcol = g2 * KP + (g1 << 6) + (o - olo);
            for (int mi = 0; mi < 4; ++mi) {
                for (int q = 0; q < 4; ++q) {
                    int row = m0 + wr * 64 + mi * 16 + lg * 4 + q;
                    float v = acc[mi][ni][q] + bias;
                    v = v * fminf(fmaxf(v + 3.0f, 0.0f), 6.0f) * (1.0f / 6.0f);
                    hbuf[(size_t)row * HROW + hcol] = f2bf(v);
                }
            }
        }
    }
}

// ---- layer 2: per m-tile 64: loop g2 0..8, dense GEMM K=576 vs W2p, + bias -> out
__global__ __launch_bounds__(256) void k2(const short* __restrict__ hbuf, const short* __restrict__ w2p,
                                          const float* __restrict__ b2, float* __restrict__ out) {
    __shared__ short As[64 * 8 * 8];     // [row64][granule8][8] 8 KB
    __shared__ short Bs[128 * 8 * 8];    // 16 KB
    const int t = threadIdx.x;
    const int m0 = blockIdx.x * 64;
    const int lane = t & 63, w = t >> 6;
    const int wr = w >> 1, wc = w & 1;   // wave tile 32 rows x 64 cols
    const int lr = lane & 15, lg = lane >> 4;

    for (int g2 = 0; g2 < NG; ++g2) {
        f32x4 acc[2][4];
        for (int mi = 0; mi < 2; ++mi) for (int ni = 0; ni < 4; ++ni) acc[mi][ni] = (f32x4){0.f,0.f,0.f,0.f};
        for (int ks = 0; ks < 9; ++ks) {   // K = 576 in chunks of 64
            __syncthreads();
            // stage A: hbuf[m0+row][g2*576 + ks*64 + col], 64x64
            for (int i = 0; i < 2; ++i) {
                int flat = (i * 256 + t) * 8;
                int row = flat >> 6, col = flat & 63;
                bf16x8 s = *(const bf16x8*)(hbuf + (size_t)(m0 + row) * HROW + g2 * KP + ks * 64 + col);
                int g = col >> 3;
                *(bf16x8*)&As[(row * 8 + (g ^ (row & 7))) * 8] = s;
            }
            // stage B: w2p[g2][row][ks*64+col], 128x64
            for (int i = 0; i < 4; ++i) {
                int flat = (i * 256 + t) * 8;
                int row = flat >> 6, col = flat & 63;
                bf16x8 s = *(const bf16x8*)(w2p + ((g2 * OG2 + row) * KP + ks * 64 + col));
                int g = col >> 3;
                *(bf16x8*)&Bs[(row * 8 + (g ^ (row & 7))) * 8] = s;
            }
            __syncthreads();
            for (int kk = 0; kk < 2; ++kk) {
                int gk = kk * 4 + lg;
                bf16x8 af[2], bfr[4];
                for (int mi = 0; mi < 2; ++mi) {
                    int row = wr * 32 + mi * 16 + lr;
                    af[mi] = *(const bf16x8*)&As[(row * 8 + (gk ^ (row & 7))) * 8];
                }
                for (int ni = 0; ni < 4; ++ni) {
                    int rb = wc * 64 + ni * 16 + lr;
                    bfr[ni] = *(const bf16x8*)&Bs[(rb * 8 + (gk ^ (rb & 7))) * 8];
                }
                for (int mi = 0; mi < 2; ++mi)
                    for (int ni = 0; ni < 4; ++ni)
                        acc[mi][ni] = __builtin_amdgcn_mfma_f32_16x16x32_bf16(af[mi], bfr[ni], acc[mi][ni], 0, 0, 0);
            }
        }
        // epilogue: + bias -> out[m][o2*9+g2] (block owns full rows -> lines merge in L2)
        for (int ni = 0; ni < 4; ++ni) {
            int o2 = wc * 64 + ni * 16 + lr;
            float bias = b2[g2 * OG2 + o2];
            for (int mi = 0; mi < 2; ++mi) {
                for (int q = 0; q < 4; ++q) {
                    int row = m0 + wr * 32 + mi * 16 + lg * 4 + q;
                    out[(size_t)row * CIN + o2 * 9 + g2] = acc[mi][ni][q] + bias;
                }
            }
        }
    }
}

extern "C" void kernel_launch(void* const* d_in, const int* in_sizes, int n_in,
                              void* d_out, int out_size, void* d_ws, size_t ws_size,
                              hipStream_t stream) {
    const float* x  = (const float*)d_in[0];
    const float* w1 = (const float*)d_in[1];
    const float* b1 = (const float*)d_in[2];
    const float* w2 = (const float*)d_in[3];
    const float* b2 = (const float*)d_in[4];
    float* out = (float*)d_out;

    short* hbuf = (short*)d_ws;                                                  // 169,869,312 B
    short* w1b  = (short*)((char*)d_ws + (size_t)MTOT * HROW * 2);               // 1,179,648 B
    short* w2p  = (short*)((char*)d_ws + (size_t)MTOT * HROW * 2 + (size_t)NG * OG1 * IG1 * 2); // 1,327,104 B

    prep_w1<<<(NG * OG1 * IG1 + 255) / 256, 256, 0, stream>>>(w1, w1b);
    prep_w2<<<(NG * OG2 * KP + 255) / 256, 256, 0, stream>>>(w2, w2p);
    k1<<<dim3(MTOT / 128, NG), 256, 0, stream>>>(x, w1b, b1, hbuf);
    k2<<<MTOT / 64, 256, 0, stream>>>(hbuf, w2p, b2, out);
}

// Round 2
// 200.119 us; speedup vs baseline: 1.6727x; 1.6727x over previous
//
#include <hip/hip_runtime.h>

typedef short bf16x8 __attribute__((ext_vector_type(8)));
typedef float f32x4 __attribute__((ext_vector_type(4)));

#define NG   9
#define CIN  1152
#define IG1  128
#define OG1  512
#define IG2  512
#define OG2  128
#define KP   576      // padded K per g2 (9 runs * 64)
#define HROW 5184     // NG * KP
#define MTOT 16384
#define OSTRIDE 1156  // LDS out-staging row stride (floats): 16B-aligned, 2-way-free banks

__device__ __forceinline__ short f2bf(float f) {
    unsigned u = __float_as_uint(f);
    u += 0x7fff + ((u >> 16) & 1);   // RNE
    return (short)(u >> 16);
}

// ---- prep: W1 fp32 -> bf16 (layout kept: [9][512][128], k contiguous)
__global__ __launch_bounds__(256) void prep_w1(const float* __restrict__ w1, short* __restrict__ w1b) {
    int i = blockIdx.x * 256 + threadIdx.x;
    if (i < NG * OG1 * IG1) w1b[i] = f2bf(w1[i]);
}

// ---- prep: W2p[g2][o2][kp] permuted + zero-padded bf16
// kp = g1*64 + r  ->  o = olo(g1,g2)+r, j = 9*o + g1 - 512*g2 ; valid iff j < 512
__global__ __launch_bounds__(256) void prep_w2(const float* __restrict__ w2, short* __restrict__ w2p) {
    int i = blockIdx.x * 256 + threadIdx.x;
    if (i >= NG * OG2 * KP) return;
    int g2  = i / (OG2 * KP);
    int rem = i - g2 * (OG2 * KP);
    int o2  = rem / KP;
    int kp  = rem - o2 * KP;
    int g1 = kp >> 6, r = kp & 63;
    int olo = (512 * g2 - g1 + 8) / 9;           // ceil((512g2-g1)/9), numerator >= 0
    int j = 9 * (olo + r) + g1 - 512 * g2;       // >= 0 by construction
    float v = (j < 512) ? w2[(g2 * OG2 + o2) * IG2 + j] : 0.0f;
    w2p[i] = f2bf(v);
}

// ---- layer 1: per (m-tile 128, g1): X[128x128] @ W1[g1]^T -> hardswish -> hbuf
__global__ __launch_bounds__(256) void k1(const float* __restrict__ x, const short* __restrict__ w1b,
                                          const float* __restrict__ b1, short* __restrict__ hbuf) {
    __shared__ short As[128 * 16 * 8];   // [row][granule16][8] XOR-swizzled, 32 KB
    __shared__ short Bs[64 * 16 * 8];    // 16 KB
    const int t = threadIdx.x;
    const int mt = blockIdx.x, g1 = blockIdx.y;
    const int m0 = mt * 128;

    // stage A: x tile 128x128 fp32 -> bf16, swizzled
    for (int i = 0; i < 8; ++i) {
        int flat = (i * 256 + t) * 8;
        int row = flat >> 7, col = flat & 127;
        const float* gp = x + (size_t)(m0 + row) * CIN + g1 * IG1 + col;
        float4 v0 = *(const float4*)gp;
        float4 v1 = *(const float4*)(gp + 4);
        bf16x8 s;
        s[0]=f2bf(v0.x); s[1]=f2bf(v0.y); s[2]=f2bf(v0.z); s[3]=f2bf(v0.w);
        s[4]=f2bf(v1.x); s[5]=f2bf(v1.y); s[6]=f2bf(v1.z); s[7]=f2bf(v1.w);
        int g = col >> 3;
        *(bf16x8*)&As[(row * 16 + (g ^ (row & 7))) * 8] = s;
    }

    const int lane = t & 63, w = t >> 6;
    const int wr = w >> 1, wc = w & 1;       // 2x2 waves; wave tile 64 rows x 32 cols
    const int lr = lane & 15, lg = lane >> 4;

    for (int nt = 0; nt < 8; ++nt) {         // o-tiles of 64 (512 total)
        __syncthreads();
        // stage B: w1b[g1][nt*64+row][col], 64x128
        for (int i = 0; i < 4; ++i) {
            int flat = (i * 256 + t) * 8;
            int row = flat >> 7, col = flat & 127;
            bf16x8 s = *(const bf16x8*)(w1b + ((g1 * OG1 + nt * 64 + row) * IG1 + col));
            int g = col >> 3;
            *(bf16x8*)&Bs[(row * 16 + (g ^ (row & 7))) * 8] = s;
        }
        __syncthreads();

        f32x4 acc[4][2];
        for (int mi = 0; mi < 4; ++mi) for (int ni = 0; ni < 2; ++ni) acc[mi][ni] = (f32x4){0.f,0.f,0.f,0.f};
        for (int kk = 0; kk < 4; ++kk) {
            int gk = kk * 4 + lg;
            bf16x8 af[4], bfr[2];
            for (int mi = 0; mi < 4; ++mi) {
                int row = wr * 64 + mi * 16 + lr;
                af[mi] = *(const bf16x8*)&As[(row * 16 + (gk ^ (row & 7))) * 8];
            }
            for (int ni = 0; ni < 2; ++ni) {
                int rb = wc * 32 + ni * 16 + lr;
                bfr[ni] = *(const bf16x8*)&Bs[(rb * 16 + (gk ^ (rb & 7))) * 8];
            }
            for (int mi = 0; mi < 4; ++mi)
                for (int ni = 0; ni < 2; ++ni)
                    acc[mi][ni] = __builtin_amdgcn_mfma_f32_16x16x32_bf16(af[mi], bfr[ni], acc[mi][ni], 0, 0, 0);
        }

        // epilogue: bias + hardswish -> bf16 -> hbuf (padded-run layout)
        for (int ni = 0; ni < 2; ++ni) {
            int o = nt * 64 + wc * 32 + ni * 16 + lr;
            float bias = b1[g1 * OG1 + o];
            int c  = 9 * o + g1;
            int g2 = c >> 9;
            int olo = (512 * g2 - g1 + 8) / 9;
            int hcol = g2 * KP + (g1 << 6) + (o - olo);
            for (int mi = 0; mi < 4; ++mi) {
                for (int q = 0; q < 4; ++q) {
                    int row = m0 + wr * 64 + mi * 16 + lg * 4 + q;
                    float v = acc[mi][ni][q] + bias;
                    v = v * fminf(fmaxf(v + 3.0f, 0.0f), 6.0f) * (1.0f / 6.0f);
                    hbuf[(size_t)row * HROW + hcol] = f2bf(v);
                }
            }
        }
    }
}

// ---- layer 2 v2: 9 waves (wave = g2), m-tile 32, full-row output via LDS staging.
// A (hidden) and B (W2p) load global->registers directly; no main-loop barriers.
__global__ __launch_bounds__(576) void k2(const short* __restrict__ hbuf, const short* __restrict__ w2p,
                                          const float* __restrict__ b2, float* __restrict__ out) {
    __shared__ float outs[32 * OSTRIDE];   // 147,968 B
    const int t = threadIdx.x;
    const int m0 = blockIdx.x * 32;
    const int g2 = t >> 6;                 // wave id = output group
    const int lane = t & 63;
    const int lr = lane & 15, lg = lane >> 4;

    f32x4 acc[2][8];
#pragma unroll
    for (int mi = 0; mi < 2; ++mi)
#pragma unroll
        for (int nc = 0; nc < 8; ++nc) acc[mi][nc] = (f32x4){0.f, 0.f, 0.f, 0.f};

    const short* Ab = hbuf + (size_t)(m0 + lr) * HROW + g2 * KP + lg * 8;
    const short* Bb = w2p + (size_t)(g2 * OG2 + lr) * KP + lg * 8;

    for (int ks = 0; ks < 3; ++ks) {       // K = 576 in 3 chunks of 192 (6 k-frags)
        bf16x8 af[2][6];
#pragma unroll
        for (int mi = 0; mi < 2; ++mi)
#pragma unroll
            for (int kf = 0; kf < 6; ++kf)
                af[mi][kf] = *(const bf16x8*)(Ab + mi * 16 * HROW + (ks * 6 + kf) * 32);
#pragma unroll
        for (int kf = 0; kf < 6; ++kf) {
            bf16x8 bv[8];
#pragma unroll
            for (int nc = 0; nc < 8; ++nc)
                bv[nc] = *(const bf16x8*)(Bb + nc * 16 * KP + (ks * 6 + kf) * 32);
#pragma unroll
            for (int nc = 0; nc < 8; ++nc)
#pragma unroll
                for (int mi = 0; mi < 2; ++mi)
                    acc[mi][nc] = __builtin_amdgcn_mfma_f32_16x16x32_bf16(af[mi][kf], bv[nc], acc[mi][nc], 0, 0, 0);
        }
    }

    // deposit this wave's stride-9 columns into LDS (2-way bank alias = free)
#pragma unroll
    for (int nc = 0; nc < 8; ++nc) {
        int o2 = nc * 16 + lr;
        float bias = b2[g2 * OG2 + o2];
        int c = o2 * 9 + g2;
#pragma unroll
        for (int mi = 0; mi < 2; ++mi)
#pragma unroll
            for (int q = 0; q < 4; ++q)
                outs[(mi * 16 + lg * 4 + q) * OSTRIDE + c] = acc[mi][nc][q] + bias;
    }
    __syncthreads();

    // coalesced full-row write: 32 rows x 1152 fp32 = 9216 float4 over 576 threads
#pragma unroll
    for (int i = 0; i < 16; ++i) {
        int f4 = i * 576 + t;
        int row = f4 / 288;
        int c4 = f4 - row * 288;
        float4 v = *(const float4*)&outs[row * OSTRIDE + c4 * 4];
        *(float4*)&out[(size_t)(m0 + row) * CIN + c4 * 4] = v;
    }
}

extern "C" void kernel_launch(void* const* d_in, const int* in_sizes, int n_in,
                              void* d_out, int out_size, void* d_ws, size_t ws_size,
                              hipStream_t stream) {
    const float* x  = (const float*)d_in[0];
    const float* w1 = (const float*)d_in[1];
    const float* b1 = (const float*)d_in[2];
    const float* w2 = (const float*)d_in[3];
    const float* b2 = (const float*)d_in[4];
    float* out = (float*)d_out;

    short* hbuf = (short*)d_ws;                                                  // 169,869,312 B
    short* w1b  = (short*)((char*)d_ws + (size_t)MTOT * HROW * 2);               // 1,179,648 B
    short* w2p  = (short*)((char*)d_ws + (size_t)MTOT * HROW * 2 + (size_t)NG * OG1 * IG1 * 2); // 1,327,104 B

    prep_w1<<<(NG * OG1 * IG1 + 255) / 256, 256, 0, stream>>>(w1, w1b);
    prep_w2<<<(NG * OG2 * KP + 255) / 256, 256, 0, stream>>>(w2, w2p);
    k1<<<dim3(MTOT / 128, NG), 256, 0, stream>>>(x, w1b, b1, hbuf);
    k2<<<MTOT / 32, 576, 0, stream>>>(hbuf, w2p, b2, out);
}